// Round 4
// baseline (335.218 us; speedup 1.0000x reference)
//
#include <hip/hip_runtime.h>

typedef float f32x8 __attribute__((ext_vector_type(8)));

#define LIF_THRESH 0.5f
#define LIF_DECAY  0.25f

// x laid out [T=4][N] float, out same. One thread = one f32x8 (32B) column
// through all 4 timesteps: 8 global_load_dwordx4 issued up front (256B MLP
// per thread), recurrence in registers, 8 nontemporal dwordx4 stores.
// Streams (205MB in + 205MB out) exceed L3 and have zero reuse -> nt hints.
__global__ __launch_bounds__(256) void lif_kernel(const f32x8* __restrict__ x,
                                                  f32x8* __restrict__ out,
                                                  int n8, int s8) {
    int i = blockIdx.x * 256 + threadIdx.x;
    if (i >= n8) return;

    const f32x8* xp = x + i;
    f32x8* op = out + i;

    f32x8 x0 = __builtin_nontemporal_load(xp);
    f32x8 x1 = __builtin_nontemporal_load(xp + s8);
    f32x8 x2 = __builtin_nontemporal_load(xp + 2 * s8);
    f32x8 x3 = __builtin_nontemporal_load(xp + 3 * s8);

    f32x8 s0, s1, s2, s3;
#pragma unroll
    for (int c = 0; c < 8; ++c) {
        float m, sp;
        m = x0[c];
        sp = (m > LIF_THRESH) ? 1.0f : 0.0f; s0[c] = sp;
        m = (sp == 0.0f ? m * LIF_DECAY : 0.0f) + x1[c];
        sp = (m > LIF_THRESH) ? 1.0f : 0.0f; s1[c] = sp;
        m = (sp == 0.0f ? m * LIF_DECAY : 0.0f) + x2[c];
        sp = (m > LIF_THRESH) ? 1.0f : 0.0f; s2[c] = sp;
        m = (sp == 0.0f ? m * LIF_DECAY : 0.0f) + x3[c];
        sp = (m > LIF_THRESH) ? 1.0f : 0.0f; s3[c] = sp;
    }

    __builtin_nontemporal_store(s0, op);
    __builtin_nontemporal_store(s1, op + s8);
    __builtin_nontemporal_store(s2, op + 2 * s8);
    __builtin_nontemporal_store(s3, op + 3 * s8);
}

extern "C" void kernel_launch(void* const* d_in, const int* in_sizes, int n_in,
                              void* d_out, int out_size, void* d_ws, size_t ws_size,
                              hipStream_t stream) {
    const float* x = (const float*)d_in[0];
    float* out = (float*)d_out;

    const int total = in_sizes[0];   // T*B*C*H*W = 51,380,224
    const int T = 4;
    const int N = total / T;         // 12,845,056
    const int n8 = N / 8;            // 1,605,632 f32x8 per timestep (exact)
    const int s8 = n8;

    const int block = 256;
    const int grid = (n8 + block - 1) / block;  // 6272 — exact, no tail

    lif_kernel<<<grid, block, 0, stream>>>((const f32x8*)x, (f32x8*)out, n8, s8);
}

// Round 5
// 324.716 us; speedup vs baseline: 1.0323x; 1.0323x over previous
//
#include <hip/hip_runtime.h>

typedef float f32x4 __attribute__((ext_vector_type(4)));

#define LIF_THRESH 0.5f
#define LIF_DECAY  0.25f

// x laid out [T=4][N] float, out same. One thread = one float4 column through
// all 4 timesteps, recurrence in registers. Plain (cached) loads/stores —
// A/B vs R2 to isolate the nontemporal-hint effect on TCC efficiency.
__global__ __launch_bounds__(256) void lif_kernel(const f32x4* __restrict__ x,
                                                  f32x4* __restrict__ out,
                                                  int n4, int s4) {
    int i = blockIdx.x * 256 + threadIdx.x;
    if (i >= n4) return;

    const f32x4* xp = x + i;
    f32x4* op = out + i;

    f32x4 x0 = xp[0];
    f32x4 x1 = xp[s4];
    f32x4 x2 = xp[2 * s4];
    f32x4 x3 = xp[3 * s4];

    f32x4 s0, s1, s2, s3;
#pragma unroll
    for (int c = 0; c < 4; ++c) {
        float m, sp;
        m = x0[c];
        sp = (m > LIF_THRESH) ? 1.0f : 0.0f; s0[c] = sp;
        m = (sp == 0.0f ? m * LIF_DECAY : 0.0f) + x1[c];
        sp = (m > LIF_THRESH) ? 1.0f : 0.0f; s1[c] = sp;
        m = (sp == 0.0f ? m * LIF_DECAY : 0.0f) + x2[c];
        sp = (m > LIF_THRESH) ? 1.0f : 0.0f; s2[c] = sp;
        m = (sp == 0.0f ? m * LIF_DECAY : 0.0f) + x3[c];
        sp = (m > LIF_THRESH) ? 1.0f : 0.0f; s3[c] = sp;
    }

    op[0]      = s0;
    op[s4]     = s1;
    op[2 * s4] = s2;
    op[3 * s4] = s3;
}

extern "C" void kernel_launch(void* const* d_in, const int* in_sizes, int n_in,
                              void* d_out, int out_size, void* d_ws, size_t ws_size,
                              hipStream_t stream) {
    const float* x = (const float*)d_in[0];
    float* out = (float*)d_out;

    const int total = in_sizes[0];   // T*B*C*H*W = 51,380,224
    const int T = 4;
    const int N = total / T;         // 12,845,056
    const int n4 = N / 4;            // 3,211,264 float4 per timestep (exact)
    const int s4 = n4;

    const int block = 256;
    const int grid = (n4 + block - 1) / block;  // 12544 — exact, no tail

    lif_kernel<<<grid, block, 0, stream>>>((const f32x4*)x, (f32x4*)out, n4, s4);
}